// Round 14
// baseline (558.246 us; speedup 1.0000x reference)
//
#include <hip/hip_runtime.h>
#include <hip/hip_bf16.h>

#define NTOK   8192
#define DMODEL 1024
#define NEXP   8
#define HFFN   4096
#define NSLOT  16384
#define MAXWL  136

typedef __bf16 bf16x8 __attribute__((ext_vector_type(8)));
typedef float  f32x4  __attribute__((ext_vector_type(4)));
typedef unsigned short u16;
typedef u16 u16x8 __attribute__((ext_vector_type(8)));

typedef const __attribute__((address_space(1))) void* gas_ptr;
typedef __attribute__((address_space(3))) void* las_ptr;

__device__ inline u16 f2b(float f) {
  __hip_bfloat16 h = __float2bfloat16(f);
  return *reinterpret_cast<u16*>(&h);
}
__device__ inline float b2f(u16 u) {
  unsigned int v = ((unsigned int)u) << 16;
  return *reinterpret_cast<float*>(&v);
}

// ---------------- router: one wave per token; fused expert-count histogram -------
__global__ void router_k(const float* __restrict__ x, const float* __restrict__ rw,
                         const float* __restrict__ rb, int* __restrict__ tok_e,
                         float* __restrict__ tok_g, int* __restrict__ counts) {
  __shared__ int h[NEXP];
  int tid = threadIdx.x;
  if (tid < NEXP) h[tid] = 0;
  __syncthreads();
  int wave = tid >> 6, lane = tid & 63;
  int t = blockIdx.x * 4 + wave;
  const float* xr = x + (size_t)t * DMODEL;
  float acc[NEXP];
#pragma unroll
  for (int e = 0; e < NEXP; e++) acc[e] = 0.f;
#pragma unroll
  for (int i = 0; i < 4; i++) {
    int d = i * 256 + lane * 4;
    float4 xv = *(const float4*)(xr + d);
#pragma unroll
    for (int e = 0; e < NEXP; e++) {
      float4 wv = *(const float4*)(rw + (size_t)e * DMODEL + d);
      acc[e] += xv.x * wv.x + xv.y * wv.y + xv.z * wv.z + xv.w * wv.w;
    }
  }
#pragma unroll
  for (int e = 0; e < NEXP; e++) {
#pragma unroll
    for (int off = 32; off > 0; off >>= 1) acc[e] += __shfl_xor(acc[e], off);
  }
  if (lane == 0) {
    float lg[NEXP];
#pragma unroll
    for (int e = 0; e < NEXP; e++) lg[e] = acc[e] + rb[e];
    int e0 = 0;
#pragma unroll
    for (int e = 1; e < NEXP; e++) if (lg[e] > lg[e0]) e0 = e;
    int e1 = (e0 == 0) ? 1 : 0;
#pragma unroll
    for (int e = 0; e < NEXP; e++) if (e != e0 && lg[e] > lg[e1]) e1 = e;
    float ex = expf(lg[e1] - lg[e0]);       // <= 1
    float g0 = 1.f / (1.f + ex);
    float g1 = ex / (1.f + ex);
    tok_e[2 * t]     = e0;  tok_e[2 * t + 1] = e1;
    tok_g[2 * t]     = g0;  tok_g[2 * t + 1] = g1;
    atomicAdd(&h[e0], 1);
    atomicAdd(&h[e1], 1);
  }
  __syncthreads();
  if (tid < NEXP && h[tid]) atomicAdd(&counts[tid], h[tid]);
}

// ---------------- offsets + 128-grain tile worklist ----------------
__global__ void offsets_k(const int* __restrict__ counts, int* __restrict__ offsets,
                          int* __restrict__ wl) {
  if (threadIdx.x == 0) {
    int s = 0;
    for (int e = 0; e < NEXP; e++) { offsets[e] = s; s += counts[e]; }
    offsets[NEXP] = s;
    int n = 0;
    for (int e = 0; e < NEXP; e++)
      for (int t = 0; t * 128 < counts[e]; ++t) wl[n++] = (e << 16) | t;
    for (int i = n; i < MAXWL; ++i) wl[i] = -1;
  }
}

__global__ void assign_k(const int* __restrict__ tok_e, int* __restrict__ cursors,
                         const int* __restrict__ offsets, int* __restrict__ row_tok,
                         int* __restrict__ slot_of) {
  __shared__ int h[NEXP], base[NEXP];
  int tid = threadIdx.x;
  if (tid < NEXP) h[tid] = 0;
  __syncthreads();
  int t = blockIdx.x * 256 + tid;
  int e0 = tok_e[2 * t], e1 = tok_e[2 * t + 1];
  int r0 = atomicAdd(&h[e0], 1);
  int r1 = atomicAdd(&h[e1], 1);
  __syncthreads();
  if (tid < NEXP) base[tid] = atomicAdd(&cursors[tid], h[tid]);
  __syncthreads();
  int s0 = offsets[e0] + base[e0] + r0;
  int s1 = offsets[e1] + base[e1] + r1;
  row_tok[s0] = t;  slot_of[2 * t] = s0;
  row_tok[s1] = t;  slot_of[2 * t + 1] = s1;
}

// ---------------- gather: xbg[slot] = bf16(x[row_tok[slot]]) ----------------
__global__ void gather_k(const float* __restrict__ x, const int* __restrict__ row_tok,
                         u16* __restrict__ xbg) {
  int idx = blockIdx.x * 256 + threadIdx.x;
  int s = idx >> 8;
  int c = (idx & 255) * 4;
  int t = row_tok[s];
  float4 v = *(const float4*)(x + (size_t)t * DMODEL + c);
  ushort4 o;
  o.x = f2b(v.x); o.y = f2b(v.y); o.z = f2b(v.z); o.w = f2b(v.w);
  *(ushort4*)(xbg + (size_t)s * DMODEL + c) = o;
}

// ---------------- weight transpose + bf16: src[e][R][C] f32 -> dst[e][C][R] bf16 ----
__global__ void wtrans_k(const float* __restrict__ src, u16* __restrict__ dst,
                         int R, int C) {
  __shared__ u16 tile[64][72];
  int e = blockIdx.z;
  int r0 = blockIdx.x * 64, c0 = blockIdx.y * 64;
  int tid = threadIdx.x;
  int tr = tid >> 2, tc = (tid & 3) * 16;
  const float* sp = src + (size_t)e * R * C + (size_t)(r0 + tr) * C + c0 + tc;
#pragma unroll
  for (int i = 0; i < 16; i += 4) {
    float4 v = *(const float4*)(sp + i);
    tile[tr][tc + i]     = f2b(v.x);
    tile[tr][tc + i + 1] = f2b(v.y);
    tile[tr][tc + i + 2] = f2b(v.z);
    tile[tr][tc + i + 3] = f2b(v.w);
  }
  __syncthreads();
  u16* dbase = dst + (size_t)e * R * C;
#pragma unroll
  for (int it = 0; it < 2; ++it) {
    int oc  = it * 32 + (tid >> 3);
    int seg = (tid & 7) * 8;
    u16x8 o;
#pragma unroll
    for (int j = 0; j < 8; ++j) o[j] = tile[seg + j][oc];
    *(u16x8*)(dbase + (size_t)(c0 + oc) * R + r0 + seg) = o;
  }
}

// ---------------- MFMA GEMM: 128x256 tile, 4 waves, BK=32, 2-deep counted --------
// A: [slot][KTOT] bf16 linear. Bt: [E][NTOT][KTOT] bf16 (row = output col).
// 4 waves (wm 0..1 x wn 0..1), per-wave output 64x128, acc[4][8] = 128 VGPR ->
// __launch_bounds__(256, 2) gives the 256-reg budget; 2 blocks/CU (96KB LDS).
// vs R12 (128x128): LDS reads/FLOP -25% ((4+8) b128 per 32 MFMA), barriers/FLOP -50%.
// Schedule identical to R12: 2-deep counted vmcnt(6), 2 barriers/K-step.
// LDS 16B-slot swizzle within 64B rows: phys = logical ^ ((row>>1)&3),
// pre-swizzled global source + XOR'd read (conflict-free).
// Raster: XCD-chunked, then y-fastest within an xt-pair (A-pair L2-hot).
// Split-K: job kq covers K cols [kq*KCHUNK, ...), writes partial kq.
template <int KTOT, int KCHUNK, int NTOT, int NY, bool RELU, bool BIAS>
__global__ __launch_bounds__(256, 2) void moe_gemm_k(
    const u16* __restrict__ A, const u16* __restrict__ Bt,
    const float* __restrict__ bias, u16* __restrict__ Out,
    const int* __restrict__ counts, const int* __restrict__ offsets,
    const int* __restrict__ wl) {
  __shared__ __align__(16) u16 Als[2 * 128 * 32];   // 2 bufs x [128][32] = 16KB
  __shared__ __align__(16) u16 Bls[2 * 256 * 32];   // 2 bufs x [256][32] = 32KB

  int nwg = gridDim.x;                              // MAXWL*NY*NKQ, %8==0
  int lid = blockIdx.x;
  int orig = (lid & 7) * (nwg >> 3) + (lid >> 3);   // XCD-chunked swizzle
  int kq   = orig / (MAXWL * NY);
  int r1   = orig - kq * (MAXWL * NY);
  int xp   = r1 / (NY * 2);                         // xt-pair id
  int r2   = r1 - xp * (NY * 2);
  int xt = (xp << 1) | (r2 & 1);
  int y  = r2 >> 1;
  int w = wl[xt];
  if (w < 0) return;
  int e   = w >> 16;
  int tr0 = (w & 0xffff) << 7;
  int cnt = counts[e];
  int seg = offsets[e];
  int n0  = y << 8;                                 // 256-col tiles

  int tid = threadIdx.x;
  int wid = tid >> 6, lane = tid & 63;
  int wm = wid >> 1, wn = wid & 1;
  int l15 = lane & 15, lhi = lane >> 4;

  // staging: thread -> (row = tid>>2 (+64j), chunk = tid&3), source pre-swizzled.
  // (row+64j)>>1 & 3 is invariant in j, so one co works for all row groups.
  int co = (((tid & 3) ^ ((tid >> 3) & 3)) << 3) + kq * KCHUNK;
  const u16* gA0 = A + (size_t)(seg + tr0 + (tid >> 2)) * KTOT + co;
  const u16* gA1 = gA0 + (size_t)64 * KTOT;
  const u16* Bte = Bt + (size_t)e * NTOT * KTOT;
  const u16* gB0 = Bte + (size_t)(n0 + (tid >> 2)) * KTOT + co;
  const u16* gB1 = gB0 + (size_t)64 * KTOT;
  const u16* gB2 = gB0 + (size_t)128 * KTOT;
  const u16* gB3 = gB0 + (size_t)192 * KTOT;
  char* Ab = (char*)Als;
  char* Bb = (char*)Bls;
  int sdst = wid << 10;   // wave-uniform 1KB slice within each 4KB row-group

  auto stage = [&](int bs, int kb) {
    __builtin_amdgcn_global_load_lds((gas_ptr)(gA0 + kb), (las_ptr)(Ab + bs * 8192 + sdst), 16, 0, 0);
    __builtin_amdgcn_global_load_lds((gas_ptr)(gA1 + kb), (las_ptr)(Ab + bs * 8192 + 4096 + sdst), 16, 0, 0);
    __builtin_amdgcn_global_load_lds((gas_ptr)(gB0 + kb), (las_ptr)(Bb + bs * 16384 + sdst), 16, 0, 0);
    __builtin_amdgcn_global_load_lds((gas_ptr)(gB1 + kb), (las_ptr)(Bb + bs * 16384 + 4096 + sdst), 16, 0, 0);
    __builtin_amdgcn_global_load_lds((gas_ptr)(gB2 + kb), (las_ptr)(Bb + bs * 16384 + 8192 + sdst), 16, 0, 0);
    __builtin_amdgcn_global_load_lds((gas_ptr)(gB3 + kb), (las_ptr)(Bb + bs * 16384 + 12288 + sdst), 16, 0, 0);
  };

  // fragment read offsets (bytes): row*64 + (chunk ^ ((row>>1)&3))*16
  int xsw = ((lhi ^ ((l15 >> 1) & 3)) << 4);
  int aoff = (wm * 64 + l15) * 64 + xsw;
  int boff = (wn * 128 + l15) * 64 + xsw;

  f32x4 acc[4][8] = {};
  constexpr int NT = KCHUNK / 32;

  stage(0, 0);                       // prologue: tile 0 in flight
  for (int kt = 0; kt < NT; ++kt) {
    int cur = kt & 1;
    if (kt + 1 < NT) {
      stage(cur ^ 1, (kt + 1) * 32);                    // tile T+1 issued early
      asm volatile("s_waitcnt vmcnt(6)" ::: "memory");  // tile T landed; T+1 in flight
    } else {
      asm volatile("s_waitcnt vmcnt(0)" ::: "memory");
    }
    __builtin_amdgcn_s_barrier();        // publish buf cur
    __builtin_amdgcn_sched_barrier(0);

    const char* ab = Ab + cur * 8192;
    const char* bb = Bb + cur * 16384;
    bf16x8 af[4], bv[8];
#pragma unroll
    for (int m = 0; m < 4; ++m) af[m] = *(const bf16x8*)(ab + aoff + m * 1024);
#pragma unroll
    for (int n = 0; n < 8; ++n) bv[n] = *(const bf16x8*)(bb + boff + n * 1024);
#pragma unroll
    for (int m = 0; m < 4; ++m)
#pragma unroll
      for (int n = 0; n < 8; ++n)
        acc[m][n] = __builtin_amdgcn_mfma_f32_16x16x32_bf16(af[m], bv[n], acc[m][n], 0, 0, 0);
    __builtin_amdgcn_s_barrier();        // readers done before T+2 overwrites cur
  }

  // split-K partial destination
  u16* outp = Out + (size_t)kq * ((size_t)NSLOT * NTOT);

  // epilogue: C/D layout col=lane&15, row=(lane>>4)*4+reg
  int cb = n0 + wn * 128 + l15;
  float bs8[8];
#pragma unroll
  for (int n = 0; n < 8; ++n) bs8[n] = 0.f;
  if (BIAS) {
    const float* bias_e = bias + (size_t)e * NTOT;
#pragma unroll
    for (int n = 0; n < 8; ++n) bs8[n] = bias_e[cb + n * 16];
  }
  int rb0 = tr0 + wm * 64 + lhi * 4;
#pragma unroll
  for (int m = 0; m < 4; ++m) {
#pragma unroll
    for (int r = 0; r < 4; ++r) {
      int gi = rb0 + m * 16 + r;
      if (gi >= cnt) continue;
      size_t orow = (size_t)(seg + gi) * NTOT + cb;
#pragma unroll
      for (int n = 0; n < 8; ++n) {
        float v = acc[m][n][r] + bs8[n];
        if (RELU) v = fmaxf(v, 0.f);
        outp[orow + n * 16] = f2b(v);
      }
    }
  }
}

// ---- combine: out[t] = g0*(y0[s0]+y1[s0]+b2[e0]) + g1*(y0[s1]+y1[s1]+b2[e1]) ----
__global__ void combine_k(const u16* __restrict__ Y, const int* __restrict__ slot_of,
                          const int* __restrict__ tok_e, const float* __restrict__ tok_g,
                          const float* __restrict__ b2, float* __restrict__ out) {
  int t = blockIdx.x;
  int d = threadIdx.x * 4;
  int s0 = slot_of[2 * t], s1 = slot_of[2 * t + 1];
  int e0 = tok_e[2 * t],  e1 = tok_e[2 * t + 1];
  float g0 = tok_g[2 * t], g1 = tok_g[2 * t + 1];
  const u16* Y1 = Y + (size_t)NSLOT * DMODEL;
  ushort4 a0 = *(const ushort4*)(Y  + (size_t)s0 * DMODEL + d);
  ushort4 a1 = *(const ushort4*)(Y1 + (size_t)s0 * DMODEL + d);
  ushort4 c0 = *(const ushort4*)(Y  + (size_t)s1 * DMODEL + d);
  ushort4 c1 = *(const ushort4*)(Y1 + (size_t)s1 * DMODEL + d);
  float4 b20 = *(const float4*)(b2 + (size_t)e0 * DMODEL + d);
  float4 b21 = *(const float4*)(b2 + (size_t)e1 * DMODEL + d);
  float4 o;
  o.x = g0 * (b2f(a0.x) + b2f(a1.x) + b20.x) + g1 * (b2f(c0.x) + b2f(c1.x) + b21.x);
  o.y = g0 * (b2f(a0.y) + b2f(a1.y) + b20.y) + g1 * (b2f(c0.y) + b2f(c1.y) + b21.y);
  o.z = g0 * (b2f(a0.z) + b2f(a1.z) + b20.z) + g1 * (b2f(c0.z) + b2f(c1.z) + b21.z);
  o.w = g0 * (b2f(a0.w) + b2f(a1.w) + b20.w) + g1 * (b2f(c0.w) + b2f(c1.w) + b21.w);
  *(float4*)(out + (size_t)t * DMODEL + d) = o;
}

extern "C" void kernel_launch(void* const* d_in, const int* in_sizes, int n_in,
                              void* d_out, int out_size, void* d_ws, size_t ws_size,
                              hipStream_t stream) {
  const float* x  = (const float*)d_in[0];
  const float* rw = (const float*)d_in[1];
  const float* rb = (const float*)d_in[2];
  const float* w1 = (const float*)d_in[3];
  const float* b1 = (const float*)d_in[4];
  const float* w2 = (const float*)d_in[5];
  const float* b2 = (const float*)d_in[6];

  char* ws = (char*)d_ws;
  size_t o = 0;
  u16* w1t = (u16*)(ws + o); o += (size_t)NEXP * HFFN * DMODEL * 2;       // 64 MiB
  u16* w2t = (u16*)(ws + o); o += (size_t)NEXP * HFFN * DMODEL * 2;       // 64 MiB
  u16* xbg = (u16*)(ws + o); o += (size_t)(NSLOT + 256) * DMODEL * 2;     // 34 MiB
  u16* hc  = (u16*)(ws + o); o += (size_t)(NSLOT + 256) * HFFN * 2;       // 136 MiB
  u16* yp  = (u16*)w1t;   // w1t dead after GEMM1; 2 bf16 partials = exactly 64 MiB
  int*   tok_e   = (int*)(ws + o);   o += NTOK * 2 * sizeof(int);
  float* tok_g   = (float*)(ws + o); o += NTOK * 2 * sizeof(float);
  int*   slot_of = (int*)(ws + o);   o += NTOK * 2 * sizeof(int);
  int*   row_tok = (int*)(ws + o);   o += NSLOT * sizeof(int);
  int*   meta    = (int*)(ws + o);   o += 32 * sizeof(int);
  int*   wl      = (int*)(ws + o);   o += MAXWL * sizeof(int);
  int* counts  = meta;
  int* cursors = meta + 8;
  int* offsets = meta + 16;

  hipMemsetAsync(meta, 0, 64, stream);
  router_k<<<NTOK / 4, 256, 0, stream>>>(x, rw, rb, tok_e, tok_g, counts);
  offsets_k<<<1, 64, 0, stream>>>(counts, offsets, wl);
  assign_k<<<NTOK / 256, 256, 0, stream>>>(tok_e, cursors, offsets, row_tok, slot_of);
  gather_k<<<NSLOT, 256, 0, stream>>>(x, row_tok, xbg);
  wtrans_k<<<dim3(DMODEL / 64, HFFN / 64, NEXP), 256, 0, stream>>>(w1, w1t, DMODEL, HFFN);
  wtrans_k<<<dim3(HFFN / 64, DMODEL / 64, NEXP), 256, 0, stream>>>(w2, w2t, HFFN, DMODEL);

  // GEMM1: xbg[slots,1024] @ w1t^T -> hc [slots,4096], bias+relu, bf16
  moe_gemm_k<DMODEL, DMODEL, HFFN, HFFN / 256, true, true>
      <<<MAXWL * (HFFN / 256), 256, 0, stream>>>(
          xbg, w1t, b1, hc, counts, offsets, wl);
  // GEMM2 (split-K=2): hc @ w2t^T -> yp[kq][slots,1024] bf16 partials (no bias)
  moe_gemm_k<HFFN, HFFN / 2, DMODEL, DMODEL / 256, false, false>
      <<<MAXWL * (DMODEL / 256) * 2, 256, 0, stream>>>(
          hc, w2t, nullptr, yp, counts, offsets, wl);

  combine_k<<<NTOK, 256, 0, stream>>>(yp, slot_of, tok_e, tok_g, b2, (float*)d_out);
}

// Round 15
// 533.588 us; speedup vs baseline: 1.0462x; 1.0462x over previous
//
#include <hip/hip_runtime.h>
#include <hip/hip_bf16.h>

#define NTOK   8192
#define DMODEL 1024
#define NEXP   8
#define HFFN   4096
#define NSLOT  16384
#define MAXWL2 72

typedef __bf16 bf16x8 __attribute__((ext_vector_type(8)));
typedef float  f32x4  __attribute__((ext_vector_type(4)));
typedef unsigned short u16;
typedef u16 u16x8 __attribute__((ext_vector_type(8)));

typedef const __attribute__((address_space(1))) void* gas_ptr;
typedef __attribute__((address_space(3))) void* las_ptr;

__device__ inline u16 f2b(float f) {
  __hip_bfloat16 h = __float2bfloat16(f);
  return *reinterpret_cast<u16*>(&h);
}
__device__ inline float b2f(u16 u) {
  unsigned int v = ((unsigned int)u) << 16;
  return *reinterpret_cast<float*>(&v);
}

// ---------------- router: one wave per token; fused expert-count histogram -------
__global__ void router_k(const float* __restrict__ x, const float* __restrict__ rw,
                         const float* __restrict__ rb, int* __restrict__ tok_e,
                         float* __restrict__ tok_g, int* __restrict__ counts) {
  __shared__ int h[NEXP];
  int tid = threadIdx.x;
  if (tid < NEXP) h[tid] = 0;
  __syncthreads();
  int wave = tid >> 6, lane = tid & 63;
  int t = blockIdx.x * 4 + wave;
  const float* xr = x + (size_t)t * DMODEL;
  float acc[NEXP];
#pragma unroll
  for (int e = 0; e < NEXP; e++) acc[e] = 0.f;
#pragma unroll
  for (int i = 0; i < 4; i++) {
    int d = i * 256 + lane * 4;
    float4 xv = *(const float4*)(xr + d);
#pragma unroll
    for (int e = 0; e < NEXP; e++) {
      float4 wv = *(const float4*)(rw + (size_t)e * DMODEL + d);
      acc[e] += xv.x * wv.x + xv.y * wv.y + xv.z * wv.z + xv.w * wv.w;
    }
  }
#pragma unroll
  for (int e = 0; e < NEXP; e++) {
#pragma unroll
    for (int off = 32; off > 0; off >>= 1) acc[e] += __shfl_xor(acc[e], off);
  }
  if (lane == 0) {
    float lg[NEXP];
#pragma unroll
    for (int e = 0; e < NEXP; e++) lg[e] = acc[e] + rb[e];
    int e0 = 0;
#pragma unroll
    for (int e = 1; e < NEXP; e++) if (lg[e] > lg[e0]) e0 = e;
    int e1 = (e0 == 0) ? 1 : 0;
#pragma unroll
    for (int e = 0; e < NEXP; e++) if (e != e0 && lg[e] > lg[e1]) e1 = e;
    float ex = expf(lg[e1] - lg[e0]);       // <= 1
    float g0 = 1.f / (1.f + ex);
    float g1 = ex / (1.f + ex);
    tok_e[2 * t]     = e0;  tok_e[2 * t + 1] = e1;
    tok_g[2 * t]     = g0;  tok_g[2 * t + 1] = g1;
    atomicAdd(&h[e0], 1);
    atomicAdd(&h[e1], 1);
  }
  __syncthreads();
  if (tid < NEXP && h[tid]) atomicAdd(&counts[tid], h[tid]);
}

// ---------------- offsets + 256-grain tile worklist ----------------
__global__ void offsets_k(const int* __restrict__ counts, int* __restrict__ offsets,
                          int* __restrict__ wl) {
  if (threadIdx.x == 0) {
    int s = 0;
    for (int e = 0; e < NEXP; e++) { offsets[e] = s; s += counts[e]; }
    offsets[NEXP] = s;
    int n = 0;
    for (int e = 0; e < NEXP; e++)
      for (int t = 0; t * 256 < counts[e]; ++t) wl[n++] = (e << 16) | t;
    for (int i = n; i < MAXWL2; ++i) wl[i] = -1;
  }
}

__global__ void assign_k(const int* __restrict__ tok_e, int* __restrict__ cursors,
                         const int* __restrict__ offsets, int* __restrict__ row_tok,
                         int* __restrict__ slot_of) {
  __shared__ int h[NEXP], base[NEXP];
  int tid = threadIdx.x;
  if (tid < NEXP) h[tid] = 0;
  __syncthreads();
  int t = blockIdx.x * 256 + tid;
  int e0 = tok_e[2 * t], e1 = tok_e[2 * t + 1];
  int r0 = atomicAdd(&h[e0], 1);
  int r1 = atomicAdd(&h[e1], 1);
  __syncthreads();
  if (tid < NEXP) base[tid] = atomicAdd(&cursors[tid], h[tid]);
  __syncthreads();
  int s0 = offsets[e0] + base[e0] + r0;
  int s1 = offsets[e1] + base[e1] + r1;
  row_tok[s0] = t;  slot_of[2 * t] = s0;
  row_tok[s1] = t;  slot_of[2 * t + 1] = s1;
}

// ---------------- gather: xbg[slot] = bf16(x[row_tok[slot]]) ----------------
__global__ void gather_k(const float* __restrict__ x, const int* __restrict__ row_tok,
                         u16* __restrict__ xbg) {
  int idx = blockIdx.x * 256 + threadIdx.x;
  int s = idx >> 8;
  int c = (idx & 255) * 4;
  int t = row_tok[s];
  float4 v = *(const float4*)(x + (size_t)t * DMODEL + c);
  ushort4 o;
  o.x = f2b(v.x); o.y = f2b(v.y); o.z = f2b(v.z); o.w = f2b(v.w);
  *(ushort4*)(xbg + (size_t)s * DMODEL + c) = o;
}

// ---------------- weight transpose + bf16: src[e][R][C] f32 -> dst[e][C][R] bf16 ----
__global__ void wtrans_k(const float* __restrict__ src, u16* __restrict__ dst,
                         int R, int C) {
  __shared__ u16 tile[64][72];
  int e = blockIdx.z;
  int r0 = blockIdx.x * 64, c0 = blockIdx.y * 64;
  int tid = threadIdx.x;
  int tr = tid >> 2, tc = (tid & 3) * 16;
  const float* sp = src + (size_t)e * R * C + (size_t)(r0 + tr) * C + c0 + tc;
#pragma unroll
  for (int i = 0; i < 16; i += 4) {
    float4 v = *(const float4*)(sp + i);
    tile[tr][tc + i]     = f2b(v.x);
    tile[tr][tc + i + 1] = f2b(v.y);
    tile[tr][tc + i + 2] = f2b(v.z);
    tile[tr][tc + i + 3] = f2b(v.w);
  }
  __syncthreads();
  u16* dbase = dst + (size_t)e * R * C;
#pragma unroll
  for (int it = 0; it < 2; ++it) {
    int oc  = it * 32 + (tid >> 3);
    int seg = (tid & 7) * 8;
    u16x8 o;
#pragma unroll
    for (int j = 0; j < 8; ++j) o[j] = tile[seg + j][oc];
    *(u16x8*)(dbase + (size_t)(c0 + oc) * R + r0 + seg) = o;
  }
}

// ---------------- 8-phase MFMA GEMM: 256x256 tile, 8 waves, BK=64, 2-deep --------
// Port of the guide's verified 8-phase template. 8 waves (wm 0..1 x wn 0..3),
// per-wave output 128x64, acc[8][4]. LDS 128KB: 2 bufs x (A 32KB + B 32KB).
// Halves = phase-read row sets: A-P1h rows {0-63,128-191}, A-P3h {64-127,192-255},
// B-P1h {0-31,64-95,128-159,192-223}, B-P2h = +32. One half staged per phase;
// 3 halves always in flight; vmcnt(6) after each phase's MFMA (tail: 4/2/0).
// Every A/B byte is ds_read exactly ONCE per K-tile (24 b128/wave: 12+4+8+0).
// Swizzle: phys16Bslot = (ks*4+lhi) ^ (l15&7); source pre-swizzled, LDS linear.
// WAR-safe: half staged into a region only after the phase barrier that follows
// the last ds_read of that region (all reads lgkmcnt(0)-completed + barrier).
template <int KTOT, int KCHUNK, int NTOT, int NY, bool RELU, bool BIAS>
__global__ __launch_bounds__(512, 2) void moe_gemm8_k(
    const u16* __restrict__ A, const u16* __restrict__ Bt,
    const float* __restrict__ bias, u16* __restrict__ Out,
    const int* __restrict__ counts, const int* __restrict__ offsets,
    const int* __restrict__ wl) {
  __shared__ __align__(16) u16 Als[2 * 256 * 64];   // 64KB
  __shared__ __align__(16) u16 Bls[2 * 256 * 64];   // 64KB

  int nwg = gridDim.x;                              // MAXWL2*NY*NKQ, %8==0
  int lid = blockIdx.x;
  int orig = (lid & 7) * (nwg >> 3) + (lid >> 3);   // XCD-chunked swizzle
  int kq   = orig / (MAXWL2 * NY);
  int r1   = orig - kq * (MAXWL2 * NY);
  int xp   = r1 / (NY * 2);                         // xt-pair id
  int r2   = r1 - xp * (NY * 2);
  int xt = (xp << 1) | (r2 & 1);
  int y  = r2 >> 1;
  int w = wl[xt];
  if (w < 0) return;
  int e   = w >> 16;
  int tr0 = (w & 0xffff) << 8;
  int cnt = counts[e];
  int seg = offsets[e];
  int n0  = y << 8;

  int t = threadIdx.x;
  int wid = t >> 6, lane = t & 63;
  int wm = wid >> 2, wn = wid & 3;
  int l15 = lane & 15, lhi = lane >> 4;
  int l7 = l15 & 7;

  // ---- staging setup: per half, thread covers 2 rows (j=0,1), 16B chunk t&7 ----
  int co = (((t & 7) ^ ((t >> 3) & 7)) << 3) + kq * KCHUNK;  // swizzled k source
  int rl = t >> 3;                     // 0..63
  const u16* Ab0 = A + (size_t)(seg + tr0) * KTOT + co;
  const u16* Bb0 = Bt + (size_t)e * NTOT * KTOT + (size_t)n0 * KTOT + co;
  const u16 *gA1[2], *gA3[2], *gB1[2], *gB2[2];
  int dA1[2], dA3[2], dB1[2], dB2[2];
#pragma unroll
  for (int j = 0; j < 2; ++j) {
    int rA1 = j * 128 + rl;            // {0-63, 128-191}
    int rA3 = 64 + j * 128 + rl;       // {64-127, 192-255}
    int rlj = j * 64 + rl;
    int rB1 = (rlj & 31) + ((rlj >> 5) << 6);   // {0-31,64-95,128-159,192-223}
    int rB2 = rB1 + 32;
    gA1[j] = Ab0 + (size_t)rA1 * KTOT;  dA1[j] = rA1 * 128 + (t & 7) * 16;
    gA3[j] = Ab0 + (size_t)rA3 * KTOT;  dA3[j] = rA3 * 128 + (t & 7) * 16;
    gB1[j] = Bb0 + (size_t)rB1 * KTOT;  dB1[j] = rB1 * 128 + (t & 7) * 16;
    gB2[j] = Bb0 + (size_t)rB2 * KTOT;  dB2[j] = rB2 * 128 + (t & 7) * 16;
  }
  char* AL = (char*)Als;
  char* BL = (char*)Bls;

  auto stA1 = [&](int b, int kt) {
#pragma unroll
    for (int j = 0; j < 2; ++j)
      __builtin_amdgcn_global_load_lds((gas_ptr)(gA1[j] + kt * 64),
          (las_ptr)(AL + b * 32768 + dA1[j]), 16, 0, 0);
  };
  auto stA3 = [&](int b, int kt) {
#pragma unroll
    for (int j = 0; j < 2; ++j)
      __builtin_amdgcn_global_load_lds((gas_ptr)(gA3[j] + kt * 64),
          (las_ptr)(AL + b * 32768 + dA3[j]), 16, 0, 0);
  };
  auto stB1 = [&](int b, int kt) {
#pragma unroll
    for (int j = 0; j < 2; ++j)
      __builtin_amdgcn_global_load_lds((gas_ptr)(gB1[j] + kt * 64),
          (las_ptr)(BL + b * 32768 + dB1[j]), 16, 0, 0);
  };
  auto stB2 = [&](int b, int kt) {
#pragma unroll
    for (int j = 0; j < 2; ++j)
      __builtin_amdgcn_global_load_lds((gas_ptr)(gB2[j] + kt * 64),
          (las_ptr)(BL + b * 32768 + dB2[j]), 16, 0, 0);
  };

  // ---- fragment reads (each byte once per K-tile) ----
  bf16x8 a[4][2], b[4][2];
  f32x4 acc[8][4] = {};

  auto rdA = [&](int bf, int grp) {        // grp 0: m0-3 (A-P1h), 1: m4-7 (A-P3h)
    const char* base = AL + bf * 32768;
    int rbase = wm * 128 + grp * 64 + l15;
#pragma unroll
    for (int mm = 0; mm < 4; ++mm) {
      int row = rbase + mm * 16;
#pragma unroll
      for (int ks = 0; ks < 2; ++ks)
        a[mm][ks] = *(const bf16x8*)(base + row * 128 + (((ks << 2) + lhi) ^ l7) * 16);
    }
  };
  auto rdB = [&](int bf, int grp) {        // grp 0: n0-1 (B-P1h), 1: n2-3 (B-P2h)
    const char* base = BL + bf * 32768;
    int rbase = wn * 64 + grp * 32 + l15;
#pragma unroll
    for (int nn = 0; nn < 2; ++nn) {
      int row = rbase + nn * 16;
#pragma unroll
      for (int ks = 0; ks < 2; ++ks)
        b[grp * 2 + nn][ks] = *(const bf16x8*)(base + row * 128 + (((ks << 2) + lhi) ^ l7) * 16);
    }
  };
  auto mf = [&](int gm, int gn) {          // 16 MFMA: quadrant (gm, gn) x K=64
    __builtin_amdgcn_s_setprio(1);
#pragma unroll
    for (int mm = 0; mm < 4; ++mm)
#pragma unroll
      for (int nn = 0; nn < 2; ++nn)
#pragma unroll
        for (int ks = 0; ks < 2; ++ks)
          acc[gm * 4 + mm][gn * 2 + nn] = __builtin_amdgcn_mfma_f32_16x16x32_bf16(
              a[mm][ks], b[gn * 2 + nn][ks], acc[gm * 4 + mm][gn * 2 + nn], 0, 0, 0);
    __builtin_amdgcn_s_setprio(0);
  };

  constexpr int NT = KCHUNK / 64;

  // ---- prologue: FIFO = [A1h0, B1h0, B2h0, A3h0, A1h1]; vm(6) lands first two --
  stA1(0, 0); stB1(0, 0); stB2(0, 0); stA3(0, 0);
  stA1(1, 1);
  asm volatile("s_waitcnt vmcnt(6)" ::: "memory");
  __builtin_amdgcn_s_barrier();
  __builtin_amdgcn_sched_barrier(0);

  for (int tt = 0; tt < NT; ++tt) {
    int cur = tt & 1, nxt = cur ^ 1;
    bool s1 = (tt + 1 < NT), s2 = (tt + 2 < NT);

    // ---- P1: read A m0-3 + B n0-1; stage B-P1h(t+1); guard B-P2h(t) ----
    rdA(cur, 0); rdB(cur, 0);
    if (s1) stB1(nxt, tt + 1);
    __builtin_amdgcn_s_barrier();
    asm volatile("s_waitcnt lgkmcnt(0)" ::: "memory");
    __builtin_amdgcn_sched_barrier(0);
    mf(0, 0);
    if (s1) asm volatile("s_waitcnt vmcnt(6)" ::: "memory");
    else    asm volatile("s_waitcnt vmcnt(2)" ::: "memory");
    __builtin_amdgcn_s_barrier();
    __builtin_amdgcn_sched_barrier(0);

    // ---- P2: read B n2-3; stage B-P2h(t+1); guard A-P3h(t) ----
    rdB(cur, 1);
    if (s1) stB2(nxt, tt + 1);
    __builtin_amdgcn_s_barrier();
    asm volatile("s_waitcnt lgkmcnt(0)" ::: "memory");
    __builtin_amdgcn_sched_barrier(0);
    mf(0, 1);
    if (s1) asm volatile("s_waitcnt vmcnt(6)" ::: "memory");
    else    asm volatile("s_waitcnt vmcnt(0)" ::: "memory");
    __builtin_amdgcn_s_barrier();
    __builtin_amdgcn_sched_barrier(0);

    // ---- P3: read A m4-7; stage A-P3h(t+1); guard A-P1h(t+1) ----
    rdA(cur, 1);
    if (s1) stA3(nxt, tt + 1);
    __builtin_amdgcn_s_barrier();
    asm volatile("s_waitcnt lgkmcnt(0)" ::: "memory");
    __builtin_amdgcn_sched_barrier(0);
    mf(1, 1);
    if (s1) asm volatile("s_waitcnt vmcnt(6)" ::: "memory");
    __builtin_amdgcn_s_barrier();
    __builtin_amdgcn_sched_barrier(0);

    // ---- P4: no reads; stage A-P1h(t+2) into cur; guard B-P1h(t+1) ----
    if (s2) stA1(cur, tt + 2);
    __builtin_amdgcn_s_barrier();
    mf(1, 0);
    if (s2)      asm volatile("s_waitcnt vmcnt(6)" ::: "memory");
    else if (s1) asm volatile("s_waitcnt vmcnt(4)" ::: "memory");
    __builtin_amdgcn_s_barrier();
    __builtin_amdgcn_sched_barrier(0);
  }

  // split-K partial destination
  u16* outp = Out + (size_t)kq * ((size_t)NSLOT * NTOT);

  // epilogue: C/D layout col=lane&15, row=(lane>>4)*4+reg
  int cb = n0 + wn * 64 + l15;
  float bs4[4] = {0.f, 0.f, 0.f, 0.f};
  if (BIAS) {
    const float* bias_e = bias + (size_t)e * NTOT;
#pragma unroll
    for (int nn = 0; nn < 4; ++nn) bs4[nn] = bias_e[cb + nn * 16];
  }
  int rb0 = tr0 + wm * 128 + lhi * 4;
#pragma unroll
  for (int mm = 0; mm < 8; ++mm) {
#pragma unroll
    for (int r = 0; r < 4; ++r) {
      int gi = rb0 + mm * 16 + r;
      if (gi >= cnt) continue;
      size_t orow = (size_t)(seg + gi) * NTOT + cb;
#pragma unroll
      for (int nn = 0; nn < 4; ++nn) {
        float v = acc[mm][nn][r] + bs4[nn];
        if (RELU) v = fmaxf(v, 0.f);
        outp[orow + nn * 16] = f2b(v);
      }
    }
  }
}

// ---- combine: out[t] = g0*(y0[s0]+y1[s0]+b2[e0]) + g1*(y0[s1]+y1[s1]+b2[e1]) ----
__global__ void combine_k(const u16* __restrict__ Y, const int* __restrict__ slot_of,
                          const int* __restrict__ tok_e, const float* __restrict__ tok_g,
                          const float* __restrict__ b2, float* __restrict__ out) {
  int t = blockIdx.x;
  int d = threadIdx.x * 4;
  int s0 = slot_of[2 * t], s1 = slot_of[2 * t + 1];
  int e0 = tok_e[2 * t],  e1 = tok_e[2 * t + 1];
  float g0 = tok_g[2 * t], g1 = tok_g[2 * t + 1];
  const u16* Y1 = Y + (size_t)NSLOT * DMODEL;
  ushort4 a0 = *(const ushort4*)(Y  + (size_t)s0 * DMODEL + d);
  ushort4 a1 = *(const ushort4*)(Y1 + (size_t)s0 * DMODEL + d);
  ushort4 c0 = *(const ushort4*)(Y  + (size_t)s1 * DMODEL + d);
  ushort4 c1 = *(const ushort4*)(Y1 + (size_t)s1 * DMODEL + d);
  float4 b20 = *(const float4*)(b2 + (size_t)e0 * DMODEL + d);
  float4 b21 = *(const float4*)(b2 + (size_t)e1 * DMODEL + d);
  float4 o;
  o.x = g0 * (b2f(a0.x) + b2f(a1.x) + b20.x) + g1 * (b2f(c0.x) + b2f(c1.x) + b21.x);
  o.y = g0 * (b2f(a0.y) + b2f(a1.y) + b20.y) + g1 * (b2f(c0.y) + b2f(c1.y) + b21.y);
  o.z = g0 * (b2f(a0.z) + b2f(a1.z) + b20.z) + g1 * (b2f(c0.z) + b2f(c1.z) + b21.z);
  o.w = g0 * (b2f(a0.w) + b2f(a1.w) + b20.w) + g1 * (b2f(c0.w) + b2f(c1.w) + b21.w);
  *(float4*)(out + (size_t)t * DMODEL + d) = o;
}

extern "C" void kernel_launch(void* const* d_in, const int* in_sizes, int n_in,
                              void* d_out, int out_size, void* d_ws, size_t ws_size,
                              hipStream_t stream) {
  const float* x  = (const float*)d_in[0];
  const float* rw = (const float*)d_in[1];
  const float* rb = (const float*)d_in[2];
  const float* w1 = (const float*)d_in[3];
  const float* b1 = (const float*)d_in[4];
  const float* w2 = (const float*)d_in[5];
  const float* b2 = (const float*)d_in[6];

  char* ws = (char*)d_ws;
  size_t o = 0;
  u16* w1t = (u16*)(ws + o); o += (size_t)NEXP * HFFN * DMODEL * 2;       // 64 MiB
  u16* w2t = (u16*)(ws + o); o += (size_t)NEXP * HFFN * DMODEL * 2;       // 64 MiB
  u16* xbg = (u16*)(ws + o); o += (size_t)(NSLOT + 256) * DMODEL * 2;     // 34 MiB
  u16* hc  = (u16*)(ws + o); o += (size_t)(NSLOT + 256) * HFFN * 2;       // 136 MiB
  u16* yp  = (u16*)w1t;   // w1t dead after GEMM1; 2 bf16 partials = exactly 64 MiB
  int*   tok_e   = (int*)(ws + o);   o += NTOK * 2 * sizeof(int);
  float* tok_g   = (float*)(ws + o); o += NTOK * 2 * sizeof(float);
  int*   slot_of = (int*)(ws + o);   o += NTOK * 2 * sizeof(int);
  int*   row_tok = (int*)(ws + o);   o += NSLOT * sizeof(int);
  int*   meta    = (int*)(ws + o);   o += 32 * sizeof(int);
  int*   wl      = (int*)(ws + o);   o += MAXWL2 * sizeof(int);
  int* counts  = meta;
  int* cursors = meta + 8;
  int* offsets = meta + 16;

  hipMemsetAsync(meta, 0, 64, stream);
  router_k<<<NTOK / 4, 256, 0, stream>>>(x, rw, rb, tok_e, tok_g, counts);
  offsets_k<<<1, 64, 0, stream>>>(counts, offsets, wl);
  assign_k<<<NTOK / 256, 256, 0, stream>>>(tok_e, cursors, offsets, row_tok, slot_of);
  gather_k<<<NSLOT, 256, 0, stream>>>(x, row_tok, xbg);
  wtrans_k<<<dim3(DMODEL / 64, HFFN / 64, NEXP), 256, 0, stream>>>(w1, w1t, DMODEL, HFFN);
  wtrans_k<<<dim3(HFFN / 64, DMODEL / 64, NEXP), 256, 0, stream>>>(w2, w2t, HFFN, DMODEL);

  // GEMM1: xbg[slots,1024] @ w1t^T -> hc [slots,4096], bias+relu, bf16
  moe_gemm8_k<DMODEL, DMODEL, HFFN, HFFN / 256, true, true>
      <<<MAXWL2 * (HFFN / 256), 512, 0, stream>>>(
          xbg, w1t, b1, hc, counts, offsets, wl);
  // GEMM2 (split-K=2): hc @ w2t^T -> yp[kq][slots,1024] bf16 partials (no bias)
  moe_gemm8_k<HFFN, HFFN / 2, DMODEL, DMODEL / 256, false, false>
      <<<MAXWL2 * (DMODEL / 256) * 2, 512, 0, stream>>>(
          hc, w2t, nullptr, yp, counts, offsets, wl);

  combine_k<<<NTOK, 256, 0, stream>>>(yp, slot_of, tok_e, tok_g, b2, (float*)d_out);
}

// Round 16
// 511.095 us; speedup vs baseline: 1.0923x; 1.0440x over previous
//
#include <hip/hip_runtime.h>
#include <hip/hip_bf16.h>

#define NTOK   8192
#define DMODEL 1024
#define NEXP   8
#define HFFN   4096
#define NSLOT  16384
#define MAXWL  136

typedef __bf16 bf16x8 __attribute__((ext_vector_type(8)));
typedef float  f32x4  __attribute__((ext_vector_type(4)));
typedef unsigned short u16;
typedef u16 u16x8 __attribute__((ext_vector_type(8)));

typedef const __attribute__((address_space(1))) void* gas_ptr;
typedef __attribute__((address_space(3))) void* las_ptr;

__device__ inline u16 f2b(float f) {
  __hip_bfloat16 h = __float2bfloat16(f);
  return *reinterpret_cast<u16*>(&h);
}
__device__ inline float b2f(u16 u) {
  unsigned int v = ((unsigned int)u) << 16;
  return *reinterpret_cast<float*>(&v);
}

// ---- router: one wave per token; emits bf16 x; fused expert-count histogram ----
__global__ void router_k(const float* __restrict__ x, const float* __restrict__ rw,
                         const float* __restrict__ rb, int* __restrict__ tok_e,
                         float* __restrict__ tok_g, int* __restrict__ counts,
                         u16* __restrict__ xb) {
  __shared__ int h[NEXP];
  int tid = threadIdx.x;
  if (tid < NEXP) h[tid] = 0;
  __syncthreads();
  int wave = tid >> 6, lane = tid & 63;
  int t = blockIdx.x * 4 + wave;
  const float* xr = x + (size_t)t * DMODEL;
  float acc[NEXP];
#pragma unroll
  for (int e = 0; e < NEXP; e++) acc[e] = 0.f;
#pragma unroll
  for (int i = 0; i < 4; i++) {
    int d = i * 256 + lane * 4;
    float4 xv = *(const float4*)(xr + d);
    ushort4 o;
    o.x = f2b(xv.x); o.y = f2b(xv.y); o.z = f2b(xv.z); o.w = f2b(xv.w);
    *(ushort4*)(xb + (size_t)t * DMODEL + d) = o;
#pragma unroll
    for (int e = 0; e < NEXP; e++) {
      float4 wv = *(const float4*)(rw + (size_t)e * DMODEL + d);
      acc[e] += xv.x * wv.x + xv.y * wv.y + xv.z * wv.z + xv.w * wv.w;
    }
  }
#pragma unroll
  for (int e = 0; e < NEXP; e++) {
#pragma unroll
    for (int off = 32; off > 0; off >>= 1) acc[e] += __shfl_xor(acc[e], off);
  }
  if (lane == 0) {
    float lg[NEXP];
#pragma unroll
    for (int e = 0; e < NEXP; e++) lg[e] = acc[e] + rb[e];
    int e0 = 0;
#pragma unroll
    for (int e = 1; e < NEXP; e++) if (lg[e] > lg[e0]) e0 = e;
    int e1 = (e0 == 0) ? 1 : 0;
#pragma unroll
    for (int e = 0; e < NEXP; e++) if (e != e0 && lg[e] > lg[e1]) e1 = e;
    float ex = expf(lg[e1] - lg[e0]);       // <= 1
    float g0 = 1.f / (1.f + ex);
    float g1 = ex / (1.f + ex);
    tok_e[2 * t]     = e0;  tok_e[2 * t + 1] = e1;
    tok_g[2 * t]     = g0;  tok_g[2 * t + 1] = g1;
    atomicAdd(&h[e0], 1);
    atomicAdd(&h[e1], 1);
  }
  __syncthreads();
  if (tid < NEXP && h[tid]) atomicAdd(&counts[tid], h[tid]);
}

// ---------------- offsets + 128-grain tile worklist ----------------
__global__ void offsets_k(const int* __restrict__ counts, int* __restrict__ offsets,
                          int* __restrict__ wl) {
  if (threadIdx.x == 0) {
    int s = 0;
    for (int e = 0; e < NEXP; e++) { offsets[e] = s; s += counts[e]; }
    offsets[NEXP] = s;
    int n = 0;
    for (int e = 0; e < NEXP; e++)
      for (int t = 0; t * 128 < counts[e]; ++t) wl[n++] = (e << 16) | t;
    for (int i = n; i < MAXWL; ++i) wl[i] = -1;
  }
}

__global__ void assign_k(const int* __restrict__ tok_e, int* __restrict__ cursors,
                         const int* __restrict__ offsets, int* __restrict__ row_tok,
                         int* __restrict__ slot_of) {
  __shared__ int h[NEXP], base[NEXP];
  int tid = threadIdx.x;
  if (tid < NEXP) h[tid] = 0;
  __syncthreads();
  int t = blockIdx.x * 256 + tid;
  int e0 = tok_e[2 * t], e1 = tok_e[2 * t + 1];
  int r0 = atomicAdd(&h[e0], 1);
  int r1 = atomicAdd(&h[e1], 1);
  __syncthreads();
  if (tid < NEXP) base[tid] = atomicAdd(&cursors[tid], h[tid]);
  __syncthreads();
  int s0 = offsets[e0] + base[e0] + r0;
  int s1 = offsets[e1] + base[e1] + r1;
  row_tok[s0] = t;  slot_of[2 * t] = s0;
  row_tok[s1] = t;  slot_of[2 * t + 1] = s1;
}

// ---------------- gather: xbg[slot] = xb[row_tok[slot]] (bf16, 8B/lane) ---------
__global__ void gather_k(const u16* __restrict__ xb, const int* __restrict__ row_tok,
                         u16* __restrict__ xbg) {
  int s = blockIdx.x;
  int c = threadIdx.x * 4;
  int t = row_tok[s];
  *(ushort4*)(xbg + (size_t)s * DMODEL + c) =
      *(const ushort4*)(xb + (size_t)t * DMODEL + c);
}

// ---------------- weight transpose + bf16: src[e][R][C] f32 -> dst[e][C][R] bf16 ----
__global__ void wtrans_k(const float* __restrict__ src, u16* __restrict__ dst,
                         int R, int C) {
  __shared__ u16 tile[64][72];
  int e = blockIdx.z;
  int r0 = blockIdx.x * 64, c0 = blockIdx.y * 64;
  int tid = threadIdx.x;
  int tr = tid >> 2, tc = (tid & 3) * 16;
  const float* sp = src + (size_t)e * R * C + (size_t)(r0 + tr) * C + c0 + tc;
#pragma unroll
  for (int i = 0; i < 16; i += 4) {
    float4 v = *(const float4*)(sp + i);
    tile[tr][tc + i]     = f2b(v.x);
    tile[tr][tc + i + 1] = f2b(v.y);
    tile[tr][tc + i + 2] = f2b(v.z);
    tile[tr][tc + i + 3] = f2b(v.w);
  }
  __syncthreads();
  u16* dbase = dst + (size_t)e * R * C;
#pragma unroll
  for (int it = 0; it < 2; ++it) {
    int oc  = it * 32 + (tid >> 3);
    int seg = (tid & 7) * 8;
    u16x8 o;
#pragma unroll
    for (int j = 0; j < 8; ++j) o[j] = tile[seg + j][oc];
    *(u16x8*)(dbase + (size_t)(c0 + oc) * R + r0 + seg) = o;
  }
}

// ---------------- MFMA GEMM: 128x128 tile, 4 waves, BK=32, 2-deep counted --------
// (R12 core, verbatim — session-best.)
// A: [slot][KTOT] bf16 linear. Bt: [E][NTOT][KTOT] bf16 (row = output col).
// 4 waves (wm 0..1 x wn 0..1), per-wave 64x64 out, acc[4][4].
// 2-deep double-buffer (32KB LDS, 4 blocks/CU) with COUNTED vmcnt(4).
// LDS 16B-slot swizzle within 64B rows: phys = logical ^ ((row>>1)&3),
// pre-swizzled global source + XOR'd read (conflict-free).
// Raster: XCD-chunked, then y-fastest within an xt-pair (A-pair L2-hot).
// Split-K: job kq covers K cols [kq*KCHUNK, ...), writes partial kq.
template <int KTOT, int KCHUNK, int NTOT, int NY, bool RELU, bool BIAS>
__global__ __launch_bounds__(256, 4) void moe_gemm_k(
    const u16* __restrict__ A, const u16* __restrict__ Bt,
    const float* __restrict__ bias, u16* __restrict__ Out,
    const int* __restrict__ counts, const int* __restrict__ offsets,
    const int* __restrict__ wl) {
  __shared__ __align__(16) u16 Als[2 * 128 * 32];   // 2 bufs x [128][32] = 16KB
  __shared__ __align__(16) u16 Bls[2 * 128 * 32];

  int nwg = gridDim.x;                              // MAXWL*NY*NKQ, %8==0
  int lid = blockIdx.x;
  int orig = (lid & 7) * (nwg >> 3) + (lid >> 3);   // XCD-chunked swizzle
  int kq   = orig / (MAXWL * NY);
  int r1   = orig - kq * (MAXWL * NY);
  int xp   = r1 / (NY * 2);                         // xt-pair id
  int r2   = r1 - xp * (NY * 2);
  int xt = (xp << 1) | (r2 & 1);
  int y  = r2 >> 1;
  int w = wl[xt];
  if (w < 0) return;
  int e   = w >> 16;
  int tr0 = (w & 0xffff) << 7;
  int cnt = counts[e];
  int seg = offsets[e];
  int n0  = y << 7;

  int tid = threadIdx.x;
  int wid = tid >> 6, lane = tid & 63;
  int wm = wid >> 1, wn = wid & 1;
  int l15 = lane & 15, lhi = lane >> 4;

  // staging: thread -> (row = tid>>2 [+64], chunk = tid&3), source pre-swizzled
  int co = (((tid & 3) ^ ((tid >> 3) & 3)) << 3) + kq * KCHUNK;
  const u16* gA0 = A + (size_t)(seg + tr0 + (tid >> 2)) * KTOT + co;
  const u16* gA1 = gA0 + (size_t)64 * KTOT;
  const u16* Bte = Bt + (size_t)e * NTOT * KTOT;
  const u16* gB0 = Bte + (size_t)(n0 + (tid >> 2)) * KTOT + co;
  const u16* gB1 = gB0 + (size_t)64 * KTOT;
  char* Ab = (char*)Als;
  char* Bb = (char*)Bls;
  int sdst = wid << 10;   // wave-uniform 1KB slice within each 4KB half

  auto stage = [&](int bs, int kb) {
    __builtin_amdgcn_global_load_lds((gas_ptr)(gA0 + kb), (las_ptr)(Ab + bs * 8192 + sdst), 16, 0, 0);
    __builtin_amdgcn_global_load_lds((gas_ptr)(gA1 + kb), (las_ptr)(Ab + bs * 8192 + 4096 + sdst), 16, 0, 0);
    __builtin_amdgcn_global_load_lds((gas_ptr)(gB0 + kb), (las_ptr)(Bb + bs * 8192 + sdst), 16, 0, 0);
    __builtin_amdgcn_global_load_lds((gas_ptr)(gB1 + kb), (las_ptr)(Bb + bs * 8192 + 4096 + sdst), 16, 0, 0);
  };

  // fragment read offsets (bytes): row*64 + (chunk ^ ((row>>1)&3))*16
  int xsw = ((lhi ^ ((l15 >> 1) & 3)) << 4);
  int aoff = (wm * 64 + l15) * 64 + xsw;
  int boff = (wn * 64 + l15) * 64 + xsw;

  f32x4 acc[4][4] = {};
  constexpr int NT = KCHUNK / 32;

  stage(0, 0);                       // prologue: tile 0 in flight
  for (int kt = 0; kt < NT; ++kt) {
    int cur = kt & 1;
    if (kt + 1 < NT) {
      stage(cur ^ 1, (kt + 1) * 32);                    // tile T+1 issued early
      asm volatile("s_waitcnt vmcnt(4)" ::: "memory");  // tile T landed; T+1 in flight
    } else {
      asm volatile("s_waitcnt vmcnt(0)" ::: "memory");
    }
    __builtin_amdgcn_s_barrier();        // publish buf cur
    __builtin_amdgcn_sched_barrier(0);

    const char* ab = Ab + cur * 8192;
    const char* bb = Bb + cur * 8192;
    bf16x8 af[4], bv[4];
#pragma unroll
    for (int m = 0; m < 4; ++m) af[m] = *(const bf16x8*)(ab + aoff + m * 1024);
#pragma unroll
    for (int n = 0; n < 4; ++n) bv[n] = *(const bf16x8*)(bb + boff + n * 1024);
#pragma unroll
    for (int m = 0; m < 4; ++m)
#pragma unroll
      for (int n = 0; n < 4; ++n)
        acc[m][n] = __builtin_amdgcn_mfma_f32_16x16x32_bf16(af[m], bv[n], acc[m][n], 0, 0, 0);
    __builtin_amdgcn_s_barrier();        // readers done before T+2 overwrites cur
  }

  // split-K partial destination
  u16* outp = Out + (size_t)kq * ((size_t)NSLOT * NTOT);

  // epilogue: C/D layout col=lane&15, row=(lane>>4)*4+reg
  int cb = n0 + wn * 64 + l15;
  float bs4[4] = {0.f, 0.f, 0.f, 0.f};
  if (BIAS) {
    const float* bias_e = bias + (size_t)e * NTOT;
#pragma unroll
    for (int n = 0; n < 4; ++n) bs4[n] = bias_e[cb + n * 16];
  }
  int rb0 = tr0 + wm * 64 + lhi * 4;
#pragma unroll
  for (int m = 0; m < 4; ++m) {
#pragma unroll
    for (int r = 0; r < 4; ++r) {
      int gi = rb0 + m * 16 + r;
      if (gi >= cnt) continue;
      size_t orow = (size_t)(seg + gi) * NTOT + cb;
#pragma unroll
      for (int n = 0; n < 4; ++n) {
        float v = acc[m][n][r] + bs4[n];
        if (RELU) v = fmaxf(v, 0.f);
        outp[orow + n * 16] = f2b(v);
      }
    }
  }
}

// ---- combine: out[t] = g0*(y0[s0]+y1[s0]+b2[e0]) + g1*(y0[s1]+y1[s1]+b2[e1]) ----
__global__ void combine_k(const u16* __restrict__ Y, const int* __restrict__ slot_of,
                          const int* __restrict__ tok_e, const float* __restrict__ tok_g,
                          const float* __restrict__ b2, float* __restrict__ out) {
  int t = blockIdx.x;
  int d = threadIdx.x * 4;
  int s0 = slot_of[2 * t], s1 = slot_of[2 * t + 1];
  int e0 = tok_e[2 * t],  e1 = tok_e[2 * t + 1];
  float g0 = tok_g[2 * t], g1 = tok_g[2 * t + 1];
  const u16* Y1 = Y + (size_t)NSLOT * DMODEL;
  ushort4 a0 = *(const ushort4*)(Y  + (size_t)s0 * DMODEL + d);
  ushort4 a1 = *(const ushort4*)(Y1 + (size_t)s0 * DMODEL + d);
  ushort4 c0 = *(const ushort4*)(Y  + (size_t)s1 * DMODEL + d);
  ushort4 c1 = *(const ushort4*)(Y1 + (size_t)s1 * DMODEL + d);
  float4 b20 = *(const float4*)(b2 + (size_t)e0 * DMODEL + d);
  float4 b21 = *(const float4*)(b2 + (size_t)e1 * DMODEL + d);
  float4 o;
  o.x = g0 * (b2f(a0.x) + b2f(a1.x) + b20.x) + g1 * (b2f(c0.x) + b2f(c1.x) + b21.x);
  o.y = g0 * (b2f(a0.y) + b2f(a1.y) + b20.y) + g1 * (b2f(c0.y) + b2f(c1.y) + b21.y);
  o.z = g0 * (b2f(a0.z) + b2f(a1.z) + b20.z) + g1 * (b2f(c0.z) + b2f(c1.z) + b21.z);
  o.w = g0 * (b2f(a0.w) + b2f(a1.w) + b20.w) + g1 * (b2f(c0.w) + b2f(c1.w) + b21.w);
  *(float4*)(out + (size_t)t * DMODEL + d) = o;
}

extern "C" void kernel_launch(void* const* d_in, const int* in_sizes, int n_in,
                              void* d_out, int out_size, void* d_ws, size_t ws_size,
                              hipStream_t stream) {
  const float* x  = (const float*)d_in[0];
  const float* rw = (const float*)d_in[1];
  const float* rb = (const float*)d_in[2];
  const float* w1 = (const float*)d_in[3];
  const float* b1 = (const float*)d_in[4];
  const float* w2 = (const float*)d_in[5];
  const float* b2 = (const float*)d_in[6];

  char* ws = (char*)d_ws;
  size_t o = 0;
  u16* w1t = (u16*)(ws + o); o += (size_t)NEXP * HFFN * DMODEL * 2;       // 64 MiB
  u16* w2t = (u16*)(ws + o); o += (size_t)NEXP * HFFN * DMODEL * 2;       // 64 MiB
  u16* xb  = (u16*)(ws + o); o += (size_t)NTOK * DMODEL * 2;              // 16 MiB
  u16* xbg = (u16*)(ws + o); o += (size_t)(NSLOT + 256) * DMODEL * 2;     // 34 MiB
  u16* hc  = (u16*)(ws + o); o += (size_t)(NSLOT + 256) * HFFN * 2;       // 136 MiB
  u16* yp  = (u16*)w1t;   // w1t dead after GEMM1; 2 bf16 partials = exactly 64 MiB
  int*   tok_e   = (int*)(ws + o);   o += NTOK * 2 * sizeof(int);
  float* tok_g   = (float*)(ws + o); o += NTOK * 2 * sizeof(float);
  int*   slot_of = (int*)(ws + o);   o += NTOK * 2 * sizeof(int);
  int*   row_tok = (int*)(ws + o);   o += NSLOT * sizeof(int);
  int*   meta    = (int*)(ws + o);   o += 32 * sizeof(int);
  int*   wl      = (int*)(ws + o);   o += MAXWL * sizeof(int);
  int* counts  = meta;
  int* cursors = meta + 8;
  int* offsets = meta + 16;

  hipMemsetAsync(meta, 0, 64, stream);
  router_k<<<NTOK / 4, 256, 0, stream>>>(x, rw, rb, tok_e, tok_g, counts, xb);
  offsets_k<<<1, 64, 0, stream>>>(counts, offsets, wl);
  assign_k<<<NTOK / 256, 256, 0, stream>>>(tok_e, cursors, offsets, row_tok, slot_of);
  gather_k<<<NSLOT, 256, 0, stream>>>(xb, row_tok, xbg);
  wtrans_k<<<dim3(DMODEL / 64, HFFN / 64, NEXP), 256, 0, stream>>>(w1, w1t, DMODEL, HFFN);
  wtrans_k<<<dim3(HFFN / 64, DMODEL / 64, NEXP), 256, 0, stream>>>(w2, w2t, HFFN, DMODEL);

  // GEMM1: xbg[slots,1024] @ w1t^T -> hc [slots,4096], bias+relu, bf16
  moe_gemm_k<DMODEL, DMODEL, HFFN, HFFN / 128, true, true>
      <<<MAXWL * (HFFN / 128), 256, 0, stream>>>(
          xbg, w1t, b1, hc, counts, offsets, wl);
  // GEMM2 (split-K=2): hc @ w2t^T -> yp[kq][slots,1024] bf16 partials (no bias)
  moe_gemm_k<HFFN, HFFN / 2, DMODEL, DMODEL / 128, false, false>
      <<<MAXWL * (DMODEL / 128) * 2, 256, 0, stream>>>(
          hc, w2t, nullptr, yp, counts, offsets, wl);

  combine_k<<<NTOK, 256, 0, stream>>>(yp, slot_of, tok_e, tok_g, b2, (float*)d_out);
}